// Round 1
// baseline (420.192 us; speedup 1.0000x reference)
//
#include <hip/hip_runtime.h>
#include <hip/hip_bf16.h>
#include <math.h>

// Problem constants (from reference setup_inputs)
constexpr int B  = 4;
constexpr int N  = 2048;
constexpr int D  = 128;
constexpr int De = 8;
constexpr float LN_EPS = 1e-5f;

// ---------------------------------------------------------------------------
// Kernel 1: single pass over e (512 MiB): copy e -> out_e AND compute
// scores[b,i,j] = ||e[b,i,j,:]||_2.  8 floats per (b,i,j), contiguous.
// ---------------------------------------------------------------------------
__global__ __launch_bounds__(256) void k_escore(const float* __restrict__ e,
                                                float* __restrict__ out_e,
                                                float* __restrict__ scores,
                                                long long total) {
    long long stride = (long long)gridDim.x * blockDim.x;
    for (long long idx = (long long)blockIdx.x * blockDim.x + threadIdx.x;
         idx < total; idx += stride) {
        const float4* src = reinterpret_cast<const float4*>(e + idx * De);
        float4 a = src[0];
        float4 b4 = src[1];
        float4* dst = reinterpret_cast<float4*>(out_e + idx * De);
        dst[0] = a;
        dst[1] = b4;
        float ss = a.x * a.x + a.y * a.y + a.z * a.z + a.w * a.w
                 + b4.x * b4.x + b4.y * b4.y + b4.z * b4.z + b4.w * b4.w;
        scores[idx] = sqrtf(ss);
    }
}

// ---------------------------------------------------------------------------
// Kernel 2: in-place row softmax over j. One block (256 threads) per row of
// 2048 floats; each thread owns 8 elements (2 x float4).
// ---------------------------------------------------------------------------
__global__ __launch_bounds__(256) void k_softmax(float* __restrict__ scores) {
    __shared__ float redmax[4];
    __shared__ float redsum[4];
    long long row = blockIdx.x;                 // b*N + i
    float* s = scores + row * (long long)N;
    int t = threadIdx.x;

    float4 v0 = reinterpret_cast<float4*>(s)[t * 2];
    float4 v1 = reinterpret_cast<float4*>(s)[t * 2 + 1];

    float m = fmaxf(fmaxf(fmaxf(v0.x, v0.y), fmaxf(v0.z, v0.w)),
                    fmaxf(fmaxf(v1.x, v1.y), fmaxf(v1.z, v1.w)));
    #pragma unroll
    for (int off = 32; off > 0; off >>= 1)
        m = fmaxf(m, __shfl_xor(m, off));
    if ((t & 63) == 0) redmax[t >> 6] = m;
    __syncthreads();
    m = fmaxf(fmaxf(redmax[0], redmax[1]), fmaxf(redmax[2], redmax[3]));

    v0.x = __expf(v0.x - m); v0.y = __expf(v0.y - m);
    v0.z = __expf(v0.z - m); v0.w = __expf(v0.w - m);
    v1.x = __expf(v1.x - m); v1.y = __expf(v1.y - m);
    v1.z = __expf(v1.z - m); v1.w = __expf(v1.w - m);

    float sum = v0.x + v0.y + v0.z + v0.w + v1.x + v1.y + v1.z + v1.w;
    #pragma unroll
    for (int off = 32; off > 0; off >>= 1)
        sum += __shfl_xor(sum, off);
    if ((t & 63) == 0) redsum[t >> 6] = sum;
    __syncthreads();
    float inv = 1.0f / (redsum[0] + redsum[1] + redsum[2] + redsum[3]);

    v0.x *= inv; v0.y *= inv; v0.z *= inv; v0.w *= inv;
    v1.x *= inv; v1.y *= inv; v1.z *= inv; v1.w *= inv;
    reinterpret_cast<float4*>(s)[t * 2]     = v0;
    reinterpret_cast<float4*>(s)[t * 2 + 1] = v1;
}

// ---------------------------------------------------------------------------
// Kernel 3: agg[b,i,:] = sum_j w[b,i,j] * h[b,j,:]   (batched GEMM, fp32 VALU)
// Tile: BM=32 rows x D=128 cols per block, BK=32. 256 threads, 4x4 micro-tile.
// w tile stored transposed in LDS ([kk][r], pad to 36 so float4 reads stay
// 16B-aligned); h tile row-major [kk][128].
// ---------------------------------------------------------------------------
__global__ __launch_bounds__(256) void k_agg(const float* __restrict__ w,
                                             const float* __restrict__ h,
                                             float* __restrict__ agg) {
    constexpr int BM = 32;
    constexpr int BK = 32;
    __shared__ float w_s[BK][BM + 4];     // [kk][r], 36 floats/row (16B-aligned rows)
    __shared__ float h_s[BK][D];          // [kk][d]

    int b  = blockIdx.y;
    int i0 = blockIdx.x * BM;
    int t  = threadIdx.x;
    int tc = t & 31;    // column group: cols tc*4 .. tc*4+3
    int tr = t >> 5;    // row group:    rows tr*4 .. tr*4+3

    const float* wb = w + ((long long)b * N + i0) * N;
    const float* hb = h + (long long)b * N * D;

    float acc[4][4] = {};

    for (int k0 = 0; k0 < N; k0 += BK) {
        // stage w tile (transposed): 1024 elems, 4 scalar loads/thread
        int jj = t & 31;
        #pragma unroll
        for (int p = 0; p < 4; ++p) {
            int r = (t >> 5) + p * 8;
            w_s[jj][r] = wb[(long long)r * N + k0 + jj];
        }
        // stage h tile: 4096 elems, 4 float4 loads/thread
        #pragma unroll
        for (int p = 0; p < 4; ++p) {
            int kk = (t >> 5) + p * 8;
            float4 hv = *reinterpret_cast<const float4*>(hb + (long long)(k0 + kk) * D + (t & 31) * 4);
            *reinterpret_cast<float4*>(&h_s[kk][(t & 31) * 4]) = hv;
        }
        __syncthreads();

        #pragma unroll
        for (int kk = 0; kk < BK; ++kk) {
            float4 wv = *reinterpret_cast<const float4*>(&w_s[kk][tr * 4]);
            float4 hv = *reinterpret_cast<const float4*>(&h_s[kk][tc * 4]);
            acc[0][0] += wv.x * hv.x; acc[0][1] += wv.x * hv.y;
            acc[0][2] += wv.x * hv.z; acc[0][3] += wv.x * hv.w;
            acc[1][0] += wv.y * hv.x; acc[1][1] += wv.y * hv.y;
            acc[1][2] += wv.y * hv.z; acc[1][3] += wv.y * hv.w;
            acc[2][0] += wv.z * hv.x; acc[2][1] += wv.z * hv.y;
            acc[2][2] += wv.z * hv.z; acc[2][3] += wv.z * hv.w;
            acc[3][0] += wv.w * hv.x; acc[3][1] += wv.w * hv.y;
            acc[3][2] += wv.w * hv.z; acc[3][3] += wv.w * hv.w;
        }
        __syncthreads();
    }

    #pragma unroll
    for (int i = 0; i < 4; ++i) {
        float4 o;
        o.x = acc[i][0]; o.y = acc[i][1]; o.z = acc[i][2]; o.w = acc[i][3];
        *reinterpret_cast<float4*>(agg + ((long long)b * N + i0 + tr * 4 + i) * D + tc * 4) = o;
    }
}

// ---------------------------------------------------------------------------
// Kernel 4: per row: z = (h+agg) @ W^T + b; LayerNorm; ReLU; + h.
// One 128-thread block per row; thread d owns output element d.
// ---------------------------------------------------------------------------
__global__ __launch_bounds__(128) void k_out(const float* __restrict__ h,
                                             const float* __restrict__ agg,
                                             const float* __restrict__ Ww,
                                             const float* __restrict__ Wb,
                                             const float* __restrict__ ln_g,
                                             const float* __restrict__ ln_b,
                                             float* __restrict__ out) {
    __shared__ __align__(16) float x_s[D];
    __shared__ float red[4];

    long long row = blockIdx.x;    // b*N + i
    int d = threadIdx.x;

    float hv = h[row * D + d];
    x_s[d] = hv + agg[row * D + d];
    __syncthreads();

    const float4* wrow = reinterpret_cast<const float4*>(Ww + (long long)d * D);
    const float4* xv   = reinterpret_cast<const float4*>(x_s);
    float z = 0.0f;
    #pragma unroll
    for (int k = 0; k < D / 4; ++k) {
        float4 wv = wrow[k];
        float4 vv = xv[k];
        z += wv.x * vv.x + wv.y * vv.y + wv.z * vv.z + wv.w * vv.w;
    }
    z += Wb[d];

    // mean over 128 (2 waves)
    float s = z;
    #pragma unroll
    for (int off = 32; off > 0; off >>= 1)
        s += __shfl_xor(s, off);
    if ((d & 63) == 0) red[d >> 6] = s;
    __syncthreads();
    float mu = (red[0] + red[1]) * (1.0f / (float)D);
    __syncthreads();

    float dev = z - mu;
    float s2 = dev * dev;
    #pragma unroll
    for (int off = 32; off > 0; off >>= 1)
        s2 += __shfl_xor(s2, off);
    if ((d & 63) == 0) red[d >> 6] = s2;
    __syncthreads();
    float var = (red[0] + red[1]) * (1.0f / (float)D);

    float y = dev * rsqrtf(var + LN_EPS) * ln_g[d] + ln_b[d];
    out[row * D + d] = fmaxf(y, 0.0f) + hv;
}

// ---------------------------------------------------------------------------
extern "C" void kernel_launch(void* const* d_in, const int* in_sizes, int n_in,
                              void* d_out, int out_size, void* d_ws, size_t ws_size,
                              hipStream_t stream) {
    const float* h    = (const float*)d_in[0];   // [B,N,D]
    const float* e    = (const float*)d_in[1];   // [B,N,N,De]
    const float* Ww   = (const float*)d_in[2];   // [D,D]
    const float* Wb   = (const float*)d_in[3];   // [D]
    const float* ln_g = (const float*)d_in[4];   // [D]
    const float* ln_b = (const float*)d_in[5];   // [D]

    float* out   = (float*)d_out;
    float* out_h = out;                                   // [B,N,D]
    float* out_e = out + (size_t)B * N * D;               // [B,N,N,De]

    float* scores = (float*)d_ws;                         // [B,N,N]  (64 MiB)
    float* agg    = scores + (size_t)B * N * N;           // [B,N,D]  (4 MiB)

    long long total = (long long)B * N * N;               // 16.7M (b,i,j) triples

    k_escore<<<4096, 256, 0, stream>>>(e, out_e, scores, total);
    k_softmax<<<B * N, 256, 0, stream>>>(scores);
    dim3 g3(N / 32, B);
    k_agg<<<g3, 256, 0, stream>>>(scores, h, agg);
    k_out<<<B * N, 128, 0, stream>>>(h, agg, Ww, Wb, ln_g, ln_b, out_h);
}

// Round 2
// 366.282 us; speedup vs baseline: 1.1472x; 1.1472x over previous
//
#include <hip/hip_runtime.h>
#include <hip/hip_bf16.h>
#include <math.h>

// Problem constants (from reference setup_inputs)
constexpr int B  = 4;
constexpr int N  = 2048;
constexpr int D  = 128;
constexpr int De = 8;
constexpr int KS = 4;              // split-K factor for agg
constexpr float LN_EPS = 1e-5f;

// ---------------------------------------------------------------------------
// Kernel 1 (fused): one block per (b,i) row.
//  - streams e[b,i,:,:] (64KB): copies to out_e AND computes norms (registers)
//  - block softmax over the 2048 norms
//  - writes w[b,i,:] (8KB)
// Traffic: 512MiB read + 512MiB+64MiB write total -> HBM-bound.
// ---------------------------------------------------------------------------
__global__ __launch_bounds__(256) void k_row(const float* __restrict__ e,
                                             float* __restrict__ out_e,
                                             float* __restrict__ w) {
    __shared__ float red[4];
    long long row = blockIdx.x;                       // b*N + i
    const float4* src = reinterpret_cast<const float4*>(e + row * (long long)N * De);
    float4*       dst = reinterpret_cast<float4*>(out_e + row * (long long)N * De);
    int t = threadIdx.x;

    float nrm[8];
    #pragma unroll
    for (int p = 0; p < 8; ++p) {
        int j = t + p * 256;
        float4 a  = src[j * 2];
        float4 b4 = src[j * 2 + 1];
        dst[j * 2]     = a;
        dst[j * 2 + 1] = b4;
        nrm[p] = sqrtf(a.x * a.x + a.y * a.y + a.z * a.z + a.w * a.w
                     + b4.x * b4.x + b4.y * b4.y + b4.z * b4.z + b4.w * b4.w);
    }

    // block max
    float m = nrm[0];
    #pragma unroll
    for (int p = 1; p < 8; ++p) m = fmaxf(m, nrm[p]);
    #pragma unroll
    for (int off = 32; off > 0; off >>= 1) m = fmaxf(m, __shfl_xor(m, off));
    if ((t & 63) == 0) red[t >> 6] = m;
    __syncthreads();
    m = fmaxf(fmaxf(red[0], red[1]), fmaxf(red[2], red[3]));
    __syncthreads();

    // exp + block sum
    float ex[8];
    float sum = 0.0f;
    #pragma unroll
    for (int p = 0; p < 8; ++p) {
        ex[p] = __expf(nrm[p] - m);
        sum += ex[p];
    }
    #pragma unroll
    for (int off = 32; off > 0; off >>= 1) sum += __shfl_xor(sum, off);
    if ((t & 63) == 0) red[t >> 6] = sum;
    __syncthreads();
    float inv = 1.0f / (red[0] + red[1] + red[2] + red[3]);

    float* wrow = w + row * (long long)N;
    #pragma unroll
    for (int p = 0; p < 8; ++p)
        wrow[t + p * 256] = ex[p] * inv;
}

// ---------------------------------------------------------------------------
// Kernel 2: split-K partial agg.
//  aggp[s][b,i,:] = sum_{j in slice s} w[b,i,j] * h[b,j,:]
// Tile: BM=32 x D=128, BK=32, 256 threads, 4x4 micro-tile.
// grid = (N/32, B, KS) = 1024 blocks -> 4 waves/SIMD.
// ---------------------------------------------------------------------------
__global__ __launch_bounds__(256) void k_agg(const float* __restrict__ w,
                                             const float* __restrict__ h,
                                             float* __restrict__ aggp) {
    constexpr int BM = 32;
    constexpr int BK = 32;
    constexpr int KC = N / KS;            // 512 k-columns per split
    __shared__ float w_s[BK][BM + 4];     // [kk][r], padded rows (16B-aligned)
    __shared__ float h_s[BK][D];          // [kk][d]

    int b  = blockIdx.y;
    int i0 = blockIdx.x * BM;
    int kbase = blockIdx.z * KC;
    int t  = threadIdx.x;
    int tc = t & 31;    // cols tc*4 .. tc*4+3
    int tr = t >> 5;    // rows tr*4 .. tr*4+3

    const float* wb = w + ((long long)b * N + i0) * N;
    const float* hb = h + (long long)b * N * D;

    float acc[4][4] = {};

    for (int k0 = kbase; k0 < kbase + KC; k0 += BK) {
        int jj = t & 31;
        #pragma unroll
        for (int p = 0; p < 4; ++p) {
            int r = (t >> 5) + p * 8;
            w_s[jj][r] = wb[(long long)r * N + k0 + jj];
        }
        #pragma unroll
        for (int p = 0; p < 4; ++p) {
            int kk = (t >> 5) + p * 8;
            float4 hv = *reinterpret_cast<const float4*>(hb + (long long)(k0 + kk) * D + (t & 31) * 4);
            *reinterpret_cast<float4*>(&h_s[kk][(t & 31) * 4]) = hv;
        }
        __syncthreads();

        #pragma unroll
        for (int kk = 0; kk < BK; ++kk) {
            float4 wv = *reinterpret_cast<const float4*>(&w_s[kk][tr * 4]);
            float4 hv = *reinterpret_cast<const float4*>(&h_s[kk][tc * 4]);
            acc[0][0] += wv.x * hv.x; acc[0][1] += wv.x * hv.y;
            acc[0][2] += wv.x * hv.z; acc[0][3] += wv.x * hv.w;
            acc[1][0] += wv.y * hv.x; acc[1][1] += wv.y * hv.y;
            acc[1][2] += wv.y * hv.z; acc[1][3] += wv.y * hv.w;
            acc[2][0] += wv.z * hv.x; acc[2][1] += wv.z * hv.y;
            acc[2][2] += wv.z * hv.z; acc[2][3] += wv.z * hv.w;
            acc[3][0] += wv.w * hv.x; acc[3][1] += wv.w * hv.y;
            acc[3][2] += wv.w * hv.z; acc[3][3] += wv.w * hv.w;
        }
        __syncthreads();
    }

    float* ap = aggp + (long long)blockIdx.z * B * N * D;
    #pragma unroll
    for (int i = 0; i < 4; ++i) {
        float4 o;
        o.x = acc[i][0]; o.y = acc[i][1]; o.z = acc[i][2]; o.w = acc[i][3];
        *reinterpret_cast<float4*>(ap + ((long long)b * N + i0 + tr * 4 + i) * D + tc * 4) = o;
    }
}

// ---------------------------------------------------------------------------
// Kernel 3: per row: x = h + sum_s aggp[s]; z = x @ W^T + b; LN; ReLU; + h.
// One 128-thread block per row.
// ---------------------------------------------------------------------------
__global__ __launch_bounds__(128) void k_out(const float* __restrict__ h,
                                             const float* __restrict__ aggp,
                                             const float* __restrict__ Ww,
                                             const float* __restrict__ Wb,
                                             const float* __restrict__ ln_g,
                                             const float* __restrict__ ln_b,
                                             float* __restrict__ out) {
    __shared__ __align__(16) float x_s[D];
    __shared__ float red[4];
    constexpr long long BND = (long long)B * N * D;

    long long row = blockIdx.x;    // b*N + i
    int d = threadIdx.x;

    float hv = h[row * D + d];
    float a = aggp[row * D + d] + aggp[BND + row * D + d]
            + aggp[2 * BND + row * D + d] + aggp[3 * BND + row * D + d];
    x_s[d] = hv + a;
    __syncthreads();

    const float4* wrow = reinterpret_cast<const float4*>(Ww + (long long)d * D);
    const float4* xv   = reinterpret_cast<const float4*>(x_s);
    float z = 0.0f;
    #pragma unroll
    for (int k = 0; k < D / 4; ++k) {
        float4 wv = wrow[k];
        float4 vv = xv[k];
        z += wv.x * vv.x + wv.y * vv.y + wv.z * vv.z + wv.w * vv.w;
    }
    z += Wb[d];

    float s = z;
    #pragma unroll
    for (int off = 32; off > 0; off >>= 1) s += __shfl_xor(s, off);
    if ((d & 63) == 0) red[d >> 6] = s;
    __syncthreads();
    float mu = (red[0] + red[1]) * (1.0f / (float)D);
    __syncthreads();

    float dev = z - mu;
    float s2 = dev * dev;
    #pragma unroll
    for (int off = 32; off > 0; off >>= 1) s2 += __shfl_xor(s2, off);
    if ((d & 63) == 0) red[d >> 6] = s2;
    __syncthreads();
    float var = (red[0] + red[1]) * (1.0f / (float)D);

    float y = dev * rsqrtf(var + LN_EPS) * ln_g[d] + ln_b[d];
    out[row * D + d] = fmaxf(y, 0.0f) + hv;
}

// ---------------------------------------------------------------------------
extern "C" void kernel_launch(void* const* d_in, const int* in_sizes, int n_in,
                              void* d_out, int out_size, void* d_ws, size_t ws_size,
                              hipStream_t stream) {
    const float* h    = (const float*)d_in[0];   // [B,N,D]
    const float* e    = (const float*)d_in[1];   // [B,N,N,De]
    const float* Ww   = (const float*)d_in[2];   // [D,D]
    const float* Wb   = (const float*)d_in[3];   // [D]
    const float* ln_g = (const float*)d_in[4];   // [D]
    const float* ln_b = (const float*)d_in[5];   // [D]

    float* out   = (float*)d_out;
    float* out_h = out;                                   // [B,N,D]
    float* out_e = out + (size_t)B * N * D;               // [B,N,N,De]

    float* w    = (float*)d_ws;                           // [B,N,N]       (64 MiB)
    float* aggp = w + (size_t)B * N * N;                  // [KS][B,N,D]   (16 MiB)

    k_row<<<B * N, 256, 0, stream>>>(e, out_e, w);
    dim3 g2(N / 32, B, KS);
    k_agg<<<g2, 256, 0, stream>>>(w, h, aggp);
    k_out<<<B * N, 128, 0, stream>>>(h, aggp, Ww, Wb, ln_g, ln_b, out_h);
}